// Round 1
// baseline (499.684 us; speedup 1.0000x reference)
//
#include <hip/hip_runtime.h>
#include <hip/hip_bf16.h>

#define B_ 4
#define L_ 4096
#define D_ 2048
#define H_ 128
#define M_ (B_ * L_)  // 16384

typedef __attribute__((ext_vector_type(8))) short bf16x8;
typedef __attribute__((ext_vector_type(4))) float f32x4;

__device__ inline unsigned short f2bf(float f) {
  union { float f; unsigned u; } v; v.f = f;
  unsigned r = v.u + 0x7FFFu + ((v.u >> 16) & 1u);
  return (unsigned short)(r >> 16);
}

// ---------------------------------------------------------------------------
// Weight transpose + bf16 convert: Wt[m][n][d] = W_m[d][n]  (fold 1/sqrt(H) into Wq)
// ---------------------------------------------------------------------------
__global__ void wconv(const float* __restrict__ Wq, const float* __restrict__ Wk,
                      const float* __restrict__ Wv, unsigned short* __restrict__ Wt) {
  int i = blockIdx.x * 256 + threadIdx.x;  // 3*128*2048 = 786432 total
  int m = i >> 18;
  int rem = i & 262143;
  int n = rem >> 11;
  int d = rem & 2047;
  const float* W = (m == 0) ? Wq : (m == 1 ? Wk : Wv);
  float val = W[(size_t)d * H_ + n];
  if (m == 0) val *= 0.08838834764831845f;  // 1/sqrt(128)
  Wt[i] = f2bf(val);
}

// ---------------------------------------------------------------------------
// QKV projection GEMM: out = x @ W  (M=16384, K=2048, N=128 per matrix)
// 128x128 tile, 4 waves (2x2), each wave 64x64 (4x4 of 16x16 frags), BK=64.
// mat 0 -> q bf16 [B*L][H]; mat 1 -> k bf16 [B*L][H]; mat 2 -> vt bf16 [B][H][L]
// ---------------------------------------------------------------------------
__global__ __launch_bounds__(256) void qkv_gemm(
    const float* __restrict__ x, const unsigned short* __restrict__ Wt,
    unsigned short* __restrict__ qo, unsigned short* __restrict__ ko,
    unsigned short* __restrict__ vt) {
  __shared__ unsigned short Als[128][72];  // +8 pad: 144B row stride, conflict-free
  __shared__ unsigned short Bls[128][72];

  int tid = threadIdx.x;
  int mat = blockIdx.y;
  int row0 = blockIdx.x * 128;
  const unsigned short* Wm = Wt + (size_t)mat * H_ * D_;
  int lane = tid & 63;
  int w = tid >> 6;
  int wr = (w >> 1) * 64, wc = (w & 1) * 64;
  int l15 = lane & 15, lhi = lane >> 4;

  f32x4 zero = {0.f, 0.f, 0.f, 0.f};
  f32x4 acc[4][4];
#pragma unroll
  for (int i = 0; i < 4; i++)
#pragma unroll
    for (int j = 0; j < 4; j++) acc[i][j] = zero;

  int ar = tid >> 4, ac = (tid & 15) * 4;   // A staging: 16 rows/pass
  int br = tid >> 3, bc = (tid & 7) * 8;    // B staging: 32 rows/pass

  for (int k0 = 0; k0 < D_; k0 += 64) {
    // stage A: x fp32 -> bf16 in LDS
#pragma unroll
    for (int i = 0; i < 8; i++) {
      int r = ar + i * 16;
      float4 xv = *reinterpret_cast<const float4*>(&x[(size_t)(row0 + r) * D_ + k0 + ac]);
      ushort4 h;
      h.x = f2bf(xv.x); h.y = f2bf(xv.y); h.z = f2bf(xv.z); h.w = f2bf(xv.w);
      *reinterpret_cast<ushort4*>(&Als[r][ac]) = h;
    }
    // stage B: Wt bf16
#pragma unroll
    for (int i = 0; i < 4; i++) {
      int r = br + i * 32;
      bf16x8 wv = *reinterpret_cast<const bf16x8*>(&Wm[(size_t)r * D_ + k0 + bc]);
      *reinterpret_cast<bf16x8*>(&Bls[r][bc]) = wv;
    }
    __syncthreads();
#pragma unroll
    for (int ks = 0; ks < 2; ks++) {
      bf16x8 af[4], bfr[4];
#pragma unroll
      for (int mi = 0; mi < 4; mi++)
        af[mi] = *reinterpret_cast<const bf16x8*>(&Als[wr + mi * 16 + l15][ks * 32 + lhi * 8]);
#pragma unroll
      for (int ni = 0; ni < 4; ni++)
        bfr[ni] = *reinterpret_cast<const bf16x8*>(&Bls[wc + ni * 16 + l15][ks * 32 + lhi * 8]);
#pragma unroll
      for (int mi = 0; mi < 4; mi++)
#pragma unroll
        for (int ni = 0; ni < 4; ni++)
          acc[mi][ni] = __builtin_amdgcn_mfma_f32_16x16x32_bf16(af[mi], bfr[ni], acc[mi][ni], 0, 0, 0);
    }
    __syncthreads();
  }

  // epilogue: C/D layout col=lane&15, row=(lane>>4)*4+reg
#pragma unroll
  for (int mi = 0; mi < 4; mi++) {
#pragma unroll
    for (int ni = 0; ni < 4; ni++) {
#pragma unroll
      for (int r = 0; r < 4; r++) {
        int m = row0 + wr + mi * 16 + lhi * 4 + r;
        int c = wc + ni * 16 + l15;
        unsigned short hv = f2bf(acc[mi][ni][r]);
        if (mat == 0) qo[(size_t)m * H_ + c] = hv;
        else if (mat == 1) ko[(size_t)m * H_ + c] = hv;
        else {
          int b = m >> 12, l = m & 4095;
          vt[((size_t)(b * H_ + c) << 12) + l] = hv;  // V transposed: [B][H][L]
        }
      }
    }
  }
}

// ---------------------------------------------------------------------------
// Flash attention, causal. 2 waves/block, 16 q-rows/wave, KVBLK=64.
// Pair tile r with 191-r for triangular load balance.
// ---------------------------------------------------------------------------
__global__ __launch_bounds__(128) void attn(
    const unsigned short* __restrict__ q, const unsigned short* __restrict__ k,
    const unsigned short* __restrict__ vt, float* __restrict__ out) {
  __shared__ unsigned short Pls[2][16][72];  // per-wave P tile, padded

  int bid = blockIdx.x;
  int batch = bid & 3;
  int rr = bid >> 2;                       // 0..127
  int tile = (rr < 64) ? rr : (191 - rr);  // pair heavy+light
  int q0 = tile * 32;
  int tid = threadIdx.x;
  int w = tid >> 6, lane = tid & 63;
  int l15 = lane & 15, lhi = lane >> 4;
  int q0w = q0 + w * 16;

  const unsigned short* qb = q + (size_t)batch * L_ * H_;
  const unsigned short* kb = k + (size_t)batch * L_ * H_;
  const unsigned short* vb = vt + (size_t)batch * H_ * L_;
  float* ob = out + (size_t)batch * L_ * H_;

  // Q fragments (A operand): row = lane&15, h-slice = (lane>>4)*8
  bf16x8 aq[4];
#pragma unroll
  for (int s = 0; s < 4; s++)
    aq[s] = *reinterpret_cast<const bf16x8*>(&qb[(size_t)(q0w + l15) * H_ + s * 32 + lhi * 8]);

  f32x4 zero = {0.f, 0.f, 0.f, 0.f};
  f32x4 o[8];
#pragma unroll
  for (int n = 0; n < 8; n++) o[n] = zero;
  float mrun[4], lrun[4];
#pragma unroll
  for (int r = 0; r < 4; r++) { mrun[r] = -1e30f; lrun[r] = 0.f; }

  int nt = (q0 >> 6) + 1;  // both waves always share the same tile count
  for (int t = 0; t < nt; t++) {
    int k0 = t * 64;
    // S = Q K^T  (scale folded into Wq)
    f32x4 s[4];
#pragma unroll
    for (int kt = 0; kt < 4; kt++) s[kt] = zero;
#pragma unroll
    for (int kt = 0; kt < 4; kt++) {
#pragma unroll
      for (int sl = 0; sl < 4; sl++) {
        bf16x8 kf = *reinterpret_cast<const bf16x8*>(
            &kb[(size_t)(k0 + kt * 16 + l15) * H_ + sl * 32 + lhi * 8]);
        s[kt] = __builtin_amdgcn_mfma_f32_16x16x32_bf16(aq[sl], kf, s[kt], 0, 0, 0);
      }
    }
    // causal mask (diagonal tiles only)
    if (k0 + 63 > q0w) {
#pragma unroll
      for (int kt = 0; kt < 4; kt++)
#pragma unroll
        for (int r = 0; r < 4; r++) {
          int key = k0 + kt * 16 + l15;
          int qr = q0w + lhi * 4 + r;
          if (key > qr) s[kt][r] = -1e30f;
        }
    }
    // online softmax: rows live at (lane>>4)*4+r, cols at lane&15
    float mx[4], al[4], rs[4];
#pragma unroll
    for (int r = 0; r < 4; r++)
      mx[r] = fmaxf(fmaxf(s[0][r], s[1][r]), fmaxf(s[2][r], s[3][r]));
#pragma unroll
    for (int r = 0; r < 4; r++) {
#pragma unroll
      for (int off = 1; off < 16; off <<= 1)
        mx[r] = fmaxf(mx[r], __shfl_xor(mx[r], off, 64));
      float mn = fmaxf(mrun[r], mx[r]);
      al[r] = __expf(mrun[r] - mn);
      mrun[r] = mn;
      rs[r] = 0.f;
    }
#pragma unroll
    for (int kt = 0; kt < 4; kt++)
#pragma unroll
      for (int r = 0; r < 4; r++) {
        float p = __expf(s[kt][r] - mrun[r]);
        s[kt][r] = p;
        rs[r] += p;
      }
#pragma unroll
    for (int r = 0; r < 4; r++) {
#pragma unroll
      for (int off = 1; off < 16; off <<= 1)
        rs[r] += __shfl_xor(rs[r], off, 64);
      lrun[r] = lrun[r] * al[r] + rs[r];
    }
#pragma unroll
    for (int n = 0; n < 8; n++)
#pragma unroll
      for (int r = 0; r < 4; r++) o[n][r] *= al[r];
    // P (D-layout) -> LDS -> A-fragment layout
#pragma unroll
    for (int kt = 0; kt < 4; kt++)
#pragma unroll
      for (int r = 0; r < 4; r++)
        Pls[w][lhi * 4 + r][kt * 16 + l15] = f2bf(s[kt][r]);
    __syncthreads();  // both waves execute identical trip counts
    bf16x8 pa[2];
#pragma unroll
    for (int ks = 0; ks < 2; ks++)
      pa[ks] = *reinterpret_cast<const bf16x8*>(&Pls[w][l15][ks * 32 + lhi * 8]);
    // O += P V   (V pre-transposed [H][L] -> contiguous B-fragments)
#pragma unroll
    for (int n = 0; n < 8; n++) {
#pragma unroll
      for (int ks = 0; ks < 2; ks++) {
        bf16x8 vf = *reinterpret_cast<const bf16x8*>(
            &vb[(size_t)(n * 16 + l15) * L_ + k0 + ks * 32 + lhi * 8]);
        o[n] = __builtin_amdgcn_mfma_f32_16x16x32_bf16(pa[ks], vf, o[n], 0, 0, 0);
      }
    }
  }
  // epilogue
#pragma unroll
  for (int n = 0; n < 8; n++)
#pragma unroll
    for (int r = 0; r < 4; r++) {
      int row = q0w + lhi * 4 + r;
      ob[(size_t)row * H_ + n * 16 + l15] = o[n][r] / lrun[r];
    }
}

extern "C" void kernel_launch(void* const* d_in, const int* in_sizes, int n_in,
                              void* d_out, int out_size, void* d_ws, size_t ws_size,
                              hipStream_t stream) {
  const float* x  = (const float*)d_in[0];
  const float* Wq = (const float*)d_in[1];
  const float* Wk = (const float*)d_in[2];
  const float* Wv = (const float*)d_in[3];

  unsigned short* ws = (unsigned short*)d_ws;
  unsigned short* Wt = ws;                   // [3][128][2048] bf16 = 1.5 MB
  unsigned short* qo = ws + 786432;          // [16384][128] bf16 = 4 MB
  unsigned short* ko = qo + (size_t)M_ * H_; // [16384][128] bf16 = 4 MB
  unsigned short* vt = ko + (size_t)M_ * H_; // [4][128][4096] bf16 = 4 MB
  float* out = (float*)d_out;

  hipLaunchKernelGGL(wconv, dim3(3072), dim3(256), 0, stream, Wq, Wk, Wv, Wt);
  hipLaunchKernelGGL(qkv_gemm, dim3(128, 3), dim3(256), 0, stream, x, Wt, qo, ko, vt);
  hipLaunchKernelGGL(attn, dim3(512), dim3(128), 0, stream, qo, ko, vt, out);
}

// Round 2
// 434.439 us; speedup vs baseline: 1.1502x; 1.1502x over previous
//
#include <hip/hip_runtime.h>
#include <hip/hip_bf16.h>

#define B_ 4
#define L_ 4096
#define D_ 2048
#define H_ 128
#define M_ (B_ * L_)  // 16384

typedef __attribute__((ext_vector_type(8))) short bf16x8;
typedef __attribute__((ext_vector_type(4))) float f32x4;

__device__ __forceinline__ unsigned short f2bf(float f) {
  union { float f; unsigned u; } v; v.f = f;
  unsigned r = v.u + 0x7FFFu + ((v.u >> 16) & 1u);
  return (unsigned short)(r >> 16);
}

__device__ __forceinline__ unsigned cvt_pk_bf16(float lo, float hi) {
  unsigned r;
  asm("v_cvt_pk_bf16_f32 %0, %1, %2" : "=v"(r) : "v"(lo), "v"(hi));
  return r;
}

__device__ __forceinline__ void async_copy16(void* lds, const void* gptr) {
  __builtin_amdgcn_global_load_lds(
      (const __attribute__((address_space(1))) unsigned int*)gptr,
      (__attribute__((address_space(3))) unsigned int*)lds, 16, 0, 0);
}

// ---------------------------------------------------------------------------
// Weight transpose + bf16 convert: Wt[m][n][d] = W_m[d][n] (1/sqrt(H) into Wq)
// ---------------------------------------------------------------------------
__global__ void wconv(const float* __restrict__ Wq, const float* __restrict__ Wk,
                      const float* __restrict__ Wv, unsigned short* __restrict__ Wt) {
  int i = blockIdx.x * 256 + threadIdx.x;  // 3*128*2048
  int m = i >> 18;
  int rem = i & 262143;
  int n = rem >> 11;
  int d = rem & 2047;
  const float* W = (m == 0) ? Wq : (m == 1 ? Wk : Wv);
  float val = W[(size_t)d * H_ + n];
  if (m == 0) val *= 0.08838834764831845f;  // 1/sqrt(128)
  Wt[i] = f2bf(val);
}

// ---------------------------------------------------------------------------
// QKV GEMM: out = x @ W. 128x128 tile, 4 waves (2x2), BK=64, global_load_lds
// with XOR-swizzled source (rule #21), fp32 A converted at frag-read.
// mat 0 -> q [B*L][H]; mat 1 -> k [B*L][H]; mat 2 -> vt [B][H][L] (transposed
// via LDS in epilogue for coalesced stores).
// ---------------------------------------------------------------------------
__global__ __launch_bounds__(256) void qkv_gemm(
    const float* __restrict__ x, const unsigned short* __restrict__ Wt,
    unsigned short* __restrict__ qo, unsigned short* __restrict__ ko,
    unsigned short* __restrict__ vt) {
  __shared__ float AlsF[128 * 64];         // 32 KB fp32 A tile (swizzled)
  __shared__ unsigned short Bls[128 * 64]; // 16 KB bf16 B tile (swizzled)

  int tid = threadIdx.x;
  int mat = blockIdx.y;
  int row0 = blockIdx.x * 128;
  const unsigned short* Wm = Wt + (size_t)mat * H_ * D_;
  int lane = tid & 63, w = tid >> 6;
  int wr = (w >> 1) * 64, wc = (w & 1) * 64;
  int l15 = lane & 15, lhi = lane >> 4;

  f32x4 zero = {0.f, 0.f, 0.f, 0.f};
  f32x4 acc[4][4];
#pragma unroll
  for (int i = 0; i < 4; i++)
#pragma unroll
    for (int j = 0; j < 4; j++) acc[i][j] = zero;

  char* Ab = (char*)AlsF;
  char* Bb = (char*)Bls;
  const char* xg = (const char*)x;
  const char* wg = (const char*)Wm;

  for (int k0 = 0; k0 < D_; k0 += 64) {
    // stage A: 32 KB fp32, linear LDS dest, inverse-swizzled global source
#pragma unroll
    for (int p = 0; p < 8; p++) {
      int o = (p * 256 + tid) * 16;
      int r = o >> 8;
      int cb = (o & 255) ^ ((r & 7) << 4);
      async_copy16(Ab + o, xg + (((size_t)(row0 + r) * D_ + k0) << 2) + cb);
    }
    // stage B: 16 KB bf16
#pragma unroll
    for (int p = 0; p < 4; p++) {
      int o = (p * 256 + tid) * 16;
      int r = o >> 7;
      int cb = (o & 127) ^ ((r & 7) << 4);
      async_copy16(Bb + o, wg + (((size_t)r * D_ + k0) << 1) + cb);
    }
    __syncthreads();
#pragma unroll
    for (int ks = 0; ks < 2; ks++) {
      bf16x8 af[4], bfr[4];
#pragma unroll
      for (int mi = 0; mi < 4; mi++) {
        int r = wr + mi * 16 + l15;
        int sw = (r & 7) << 4;
        int cb = ks * 128 + lhi * 32;
        float4 lo = *(const float4*)(Ab + r * 256 + (cb ^ sw));
        float4 hi = *(const float4*)(Ab + r * 256 + ((cb + 16) ^ sw));
        union { bf16x8 v; unsigned u[4]; } t;
        t.u[0] = cvt_pk_bf16(lo.x, lo.y);
        t.u[1] = cvt_pk_bf16(lo.z, lo.w);
        t.u[2] = cvt_pk_bf16(hi.x, hi.y);
        t.u[3] = cvt_pk_bf16(hi.z, hi.w);
        af[mi] = t.v;
      }
#pragma unroll
      for (int ni = 0; ni < 4; ni++) {
        int r = wc + ni * 16 + l15;
        int sw = (r & 7) << 4;
        int cb = ks * 64 + lhi * 16;
        bfr[ni] = *(const bf16x8*)(Bb + r * 128 + (cb ^ sw));
      }
#pragma unroll
      for (int mi = 0; mi < 4; mi++)
#pragma unroll
        for (int ni = 0; ni < 4; ni++)
          acc[mi][ni] = __builtin_amdgcn_mfma_f32_16x16x32_bf16(af[mi], bfr[ni], acc[mi][ni], 0, 0, 0);
    }
    __syncthreads();
  }

  // epilogue: C/D layout col=lane&15, row=(lane>>4)*4+reg
  if (mat < 2) {
    unsigned short* dst = (mat == 0) ? qo : ko;
#pragma unroll
    for (int mi = 0; mi < 4; mi++)
#pragma unroll
      for (int ni = 0; ni < 4; ni++)
#pragma unroll
        for (int r = 0; r < 4; r++) {
          int m = row0 + wr + mi * 16 + lhi * 4 + r;
          int cc = wc + ni * 16 + l15;
          dst[(size_t)m * H_ + cc] = f2bf(acc[mi][ni][r]);
        }
  } else {
    // V: transpose 64x64 wave tile via LDS (reuse AlsF), coalesced 16B stores
    unsigned short(*Tls)[32][68] = (unsigned short(*)[32][68])AlsF;  // 17.4 KB
    int b = row0 >> 12;
    int l0 = row0 & 4095;
#pragma unroll
    for (int p = 0; p < 2; p++) {
#pragma unroll
      for (int ni2 = 0; ni2 < 2; ni2++) {
        int ni = 2 * p + ni2;
#pragma unroll
        for (int mi = 0; mi < 4; mi++)
#pragma unroll
          for (int r = 0; r < 4; r++)
            Tls[w][ni2 * 16 + l15][mi * 16 + lhi * 4 + r] = f2bf(acc[mi][ni][r]);
      }
      int cl = lane >> 1;
      int mh = (lane & 1) * 32;
      int h = wc + p * 32 + cl;
#pragma unroll
      for (int j = 0; j < 4; j++) {
        bf16x8 v = *(const bf16x8*)&Tls[w][cl][mh + j * 8];
        *(bf16x8*)&vt[(((size_t)(b * H_ + h)) << 12) + l0 + wr + mh + j * 8] = v;
      }
    }
  }
}

// ---------------------------------------------------------------------------
// Flash attention partials. Grid 2048: (batch 4) x (kv-chunk 4) x (q-tile 128,
// heavy-first). 2 independent waves x 16 q-rows, KVBLK=64, CHUNK=1024 keys.
// Writes unnormalized (O, m, l) partials.
// ---------------------------------------------------------------------------
__global__ __launch_bounds__(128) void attn(
    const unsigned short* __restrict__ q, const unsigned short* __restrict__ k,
    const unsigned short* __restrict__ vt, float* __restrict__ po,
    float* __restrict__ pm, float* __restrict__ pl) {
  __shared__ unsigned short Pls[2][16][72];

  int bid = blockIdx.x;
  int t = 127 - (bid & 127);
  int c = (bid >> 7) & 3;
  int b = bid >> 9;
  int kstart = c << 10;
  int kcap = (t + 1) << 5;
  if (kstart >= kcap) return;
  int kend = min(kstart + 1024, kcap);
  int nt = (kend - kstart + 63) >> 6;

  int tid = threadIdx.x;
  int w = tid >> 6, lane = tid & 63;
  int l15 = lane & 15, lhi = lane >> 4;
  int q0 = t << 5;
  int q0w = q0 + w * 16;

  const unsigned short* qb = q + ((size_t)b << 12) * H_;
  const unsigned short* kb = k + ((size_t)b << 12) * H_;
  const unsigned short* vb = vt + ((size_t)b * H_ << 12);

  bf16x8 aq[4];
#pragma unroll
  for (int s = 0; s < 4; s++)
    aq[s] = *reinterpret_cast<const bf16x8*>(&qb[(size_t)(q0w + l15) * H_ + s * 32 + lhi * 8]);

  f32x4 zero = {0.f, 0.f, 0.f, 0.f};
  f32x4 o[8];
#pragma unroll
  for (int n = 0; n < 8; n++) o[n] = zero;
  float mrun[4], lrun[4];
#pragma unroll
  for (int r = 0; r < 4; r++) { mrun[r] = -1e30f; lrun[r] = 0.f; }

  for (int ti = 0; ti < nt; ti++) {
    int k0 = kstart + ti * 64;
    f32x4 s[4];
#pragma unroll
    for (int kt = 0; kt < 4; kt++) s[kt] = zero;
#pragma unroll
    for (int kt = 0; kt < 4; kt++) {
#pragma unroll
      for (int sl = 0; sl < 4; sl++) {
        bf16x8 kf = *reinterpret_cast<const bf16x8*>(
            &kb[(size_t)(k0 + kt * 16 + l15) * H_ + sl * 32 + lhi * 8]);
        s[kt] = __builtin_amdgcn_mfma_f32_16x16x32_bf16(aq[sl], kf, s[kt], 0, 0, 0);
      }
    }
    if (k0 + 63 > q0w) {  // causal mask (covers chunk-tail over-read too)
#pragma unroll
      for (int kt = 0; kt < 4; kt++)
#pragma unroll
        for (int r = 0; r < 4; r++) {
          int key = k0 + kt * 16 + l15;
          int qr = q0w + lhi * 4 + r;
          if (key > qr) s[kt][r] = -1e30f;
        }
    }
    float mx[4], al[4], rs[4];
#pragma unroll
    for (int r = 0; r < 4; r++)
      mx[r] = fmaxf(fmaxf(s[0][r], s[1][r]), fmaxf(s[2][r], s[3][r]));
#pragma unroll
    for (int r = 0; r < 4; r++) {
#pragma unroll
      for (int off = 1; off < 16; off <<= 1)
        mx[r] = fmaxf(mx[r], __shfl_xor(mx[r], off, 64));
      float mn = fmaxf(mrun[r], mx[r]);
      al[r] = __expf(mrun[r] - mn);
      mrun[r] = mn;
      rs[r] = 0.f;
    }
#pragma unroll
    for (int kt = 0; kt < 4; kt++)
#pragma unroll
      for (int r = 0; r < 4; r++) {
        float p = __expf(s[kt][r] - mrun[r]);
        s[kt][r] = p;
        rs[r] += p;
      }
#pragma unroll
    for (int r = 0; r < 4; r++) {
#pragma unroll
      for (int off = 1; off < 16; off <<= 1)
        rs[r] += __shfl_xor(rs[r], off, 64);
      lrun[r] = lrun[r] * al[r] + rs[r];
    }
#pragma unroll
    for (int n = 0; n < 8; n++)
#pragma unroll
      for (int r = 0; r < 4; r++) o[n][r] *= al[r];
#pragma unroll
    for (int kt = 0; kt < 4; kt++)
#pragma unroll
      for (int r = 0; r < 4; r++)
        Pls[w][lhi * 4 + r][kt * 16 + l15] = f2bf(s[kt][r]);
    // per-wave LDS roundtrip; no barrier needed (DS ops in-order per wave)
    bf16x8 pa[2];
#pragma unroll
    for (int ks = 0; ks < 2; ks++)
      pa[ks] = *reinterpret_cast<const bf16x8*>(&Pls[w][l15][ks * 32 + lhi * 8]);
#pragma unroll
    for (int n = 0; n < 8; n++) {
#pragma unroll
      for (int ks = 0; ks < 2; ks++) {
        bf16x8 vf = *reinterpret_cast<const bf16x8*>(
            &vb[(size_t)(n * 16 + l15) * L_ + k0 + ks * 32 + lhi * 8]);
        o[n] = __builtin_amdgcn_mfma_f32_16x16x32_bf16(pa[ks], vf, o[n], 0, 0, 0);
      }
    }
  }

  int slot = ((b << 7) + t) * 4 + c;
  float* pob = po + ((size_t)slot << 12);
#pragma unroll
  for (int n = 0; n < 8; n++)
#pragma unroll
    for (int r = 0; r < 4; r++)
      pob[(w * 16 + lhi * 4 + r) * 128 + n * 16 + l15] = o[n][r];
  if (l15 == 0) {
#pragma unroll
    for (int r = 0; r < 4; r++) {
      pm[slot * 32 + w * 16 + lhi * 4 + r] = mrun[r];
      pl[slot * 32 + w * 16 + lhi * 4 + r] = lrun[r];
    }
  }
}

// ---------------------------------------------------------------------------
// Combine partials: per (b, q-tile), merge <=4 chunks with rescale, normalize.
// ---------------------------------------------------------------------------
__global__ __launch_bounds__(256) void combine(
    const float* __restrict__ po, const float* __restrict__ pm,
    const float* __restrict__ pl, float* __restrict__ out) {
  int bid = blockIdx.x;  // b*128 + t
  int b = bid >> 7, t = bid & 127;
  int nc = (((t + 1) << 5) + 1023) >> 10;
  int tid = threadIdx.x;
  int row = tid >> 3;
  int hb = (tid & 7) << 4;
  int base = bid * 4;

  float M = -1e30f;
  for (int ci = 0; ci < nc; ci++) M = fmaxf(M, pm[(base + ci) * 32 + row]);
  float L = 0.f;
  float a[16];
#pragma unroll
  for (int j = 0; j < 16; j++) a[j] = 0.f;
  for (int ci = 0; ci < nc; ci++) {
    int sl = base + ci;
    float wgt = __expf(pm[sl * 32 + row] - M);
    L += pl[sl * 32 + row] * wgt;
    const float* p = po + ((size_t)sl << 12) + row * 128 + hb;
#pragma unroll
    for (int j = 0; j < 4; j++) {
      float4 v = *(const float4*)(p + j * 4);
      a[j * 4 + 0] += v.x * wgt;
      a[j * 4 + 1] += v.y * wgt;
      a[j * 4 + 2] += v.z * wgt;
      a[j * 4 + 3] += v.w * wgt;
    }
  }
  float inv = 1.f / L;
  float* ob = out + ((size_t)((b << 12) + (t << 5) + row)) * 128 + hb;
#pragma unroll
  for (int j = 0; j < 16; j++) ob[j] = a[j] * inv;
}

extern "C" void kernel_launch(void* const* d_in, const int* in_sizes, int n_in,
                              void* d_out, int out_size, void* d_ws, size_t ws_size,
                              hipStream_t stream) {
  const float* x  = (const float*)d_in[0];
  const float* Wq = (const float*)d_in[1];
  const float* Wk = (const float*)d_in[2];
  const float* Wv = (const float*)d_in[3];

  unsigned short* ws = (unsigned short*)d_ws;
  unsigned short* Wt = ws;                         // 1.5 MB
  unsigned short* qo = ws + 786432;                // 4 MB
  unsigned short* ko = qo + (size_t)M_ * H_;       // 4 MB
  unsigned short* vt = ko + (size_t)M_ * H_;       // 4 MB
  float* po = (float*)(vt + (size_t)M_ * H_);      // 33.5 MB (2048 slots x 32 x 128)
  float* pm = po + (size_t)2048 * 4096;            // 0.25 MB
  float* pl = pm + 2048 * 32;                      // 0.25 MB
  float* out = (float*)d_out;

  hipLaunchKernelGGL(wconv, dim3(3072), dim3(256), 0, stream, Wq, Wk, Wv, Wt);
  hipLaunchKernelGGL(qkv_gemm, dim3(128, 3), dim3(256), 0, stream, x, Wt, qo, ko, vt);
  hipLaunchKernelGGL(attn, dim3(2048), dim3(128), 0, stream, qo, ko, vt, po, pm, pl);
  hipLaunchKernelGGL(combine, dim3(512), dim3(256), 0, stream, po, pm, pl, out);
}

// Round 3
// 431.802 us; speedup vs baseline: 1.1572x; 1.0061x over previous
//
#include <hip/hip_runtime.h>
#include <hip/hip_bf16.h>

#define B_ 4
#define L_ 4096
#define D_ 2048
#define H_ 128
#define M_ (B_ * L_)  // 16384

typedef __attribute__((ext_vector_type(8))) short bf16x8;
typedef __attribute__((ext_vector_type(4))) float f32x4;
typedef __attribute__((ext_vector_type(16))) float f32x16;

__device__ __forceinline__ unsigned short f2bf(float f) {
  union { float f; unsigned u; } v; v.f = f;
  unsigned r = v.u + 0x7FFFu + ((v.u >> 16) & 1u);
  return (unsigned short)(r >> 16);
}

__device__ __forceinline__ unsigned cvt_pk_bf16(float lo, float hi) {
  unsigned r;
  asm("v_cvt_pk_bf16_f32 %0, %1, %2" : "=v"(r) : "v"(lo), "v"(hi));
  return r;
}

__device__ __forceinline__ void async_copy16(void* lds, const void* gptr) {
  __builtin_amdgcn_global_load_lds(
      (const __attribute__((address_space(1))) unsigned int*)gptr,
      (__attribute__((address_space(3))) unsigned int*)lds, 16, 0, 0);
}

// ---------------------------------------------------------------------------
// Weight convert: Wt row R = 96*(n>>5) + 32*mat + (n&31), cols = d (bf16).
// Interleaved so each gemm wave's 96 columns = same n-range of all 3 mats.
// 1/sqrt(128) folded into Wq.
// ---------------------------------------------------------------------------
__global__ void wconv(const float* __restrict__ Wq, const float* __restrict__ Wk,
                      const float* __restrict__ Wv, unsigned short* __restrict__ Wt) {
  int i = blockIdx.x * 256 + threadIdx.x;  // 3*128*2048
  int m = i >> 18;
  int rem = i & 262143;
  int n = rem >> 11;
  int d = rem & 2047;
  const float* W = (m == 0) ? Wq : (m == 1 ? Wk : Wv);
  float val = W[(size_t)d * H_ + n];
  if (m == 0) val *= 0.08838834764831845f;
  int R = 96 * (n >> 5) + 32 * m + (n & 31);
  Wt[(size_t)R * D_ + d] = f2bf(val);
}

// ---------------------------------------------------------------------------
// Fused QKV GEMM: x[16384,2048]fp32 @ Wt^T -> q,k [B*L][H] bf16, vt [B][H][L].
// BM=64, BN=384 (3 mats), BK=64, 512 thr (8 waves: 2 row x 4 col groups),
// double-buffered LDS, global_load_lds w16, XOR-swizzled (rule #21).
// ---------------------------------------------------------------------------
__global__ __launch_bounds__(512) void qkv_gemm(
    const float* __restrict__ x, const unsigned short* __restrict__ Wt,
    unsigned short* __restrict__ qo, unsigned short* __restrict__ ko,
    unsigned short* __restrict__ vt) {
  __shared__ __align__(16) char Ab[2][16384];  // fp32 A [64][64] swizzled
  __shared__ __align__(16) char Bb[2][49152];  // bf16 B [384][64] swizzled

  int tid = threadIdx.x;
  int row0 = blockIdx.x * 64;
  int lane = tid & 63, w = tid >> 6;
  int wrow = (w >> 2) * 32;  // 0 or 32
  int g = w & 3;             // column group: n-range [32g, 32g+32) of each mat
  int l15 = lane & 15, lhi = lane >> 4;

  f32x4 zero = {0.f, 0.f, 0.f, 0.f};
  f32x4 acc[2][6];
#pragma unroll
  for (int i = 0; i < 2; i++)
#pragma unroll
    for (int j = 0; j < 6; j++) acc[i][j] = zero;

  const char* xg = (const char*)x;
  const char* wg = (const char*)Wt;

  // prologue stage k0=0 into buf 0
#pragma unroll
  for (int p = 0; p < 2; p++) {
    int o = (p * 512 + tid) * 16;
    int r = o >> 8;
    int cb = (o & 255) ^ ((r & 7) << 4);
    async_copy16(Ab[0] + o, xg + (((size_t)(row0 + r) * D_) << 2) + cb);
  }
#pragma unroll
  for (int p = 0; p < 6; p++) {
    int o = (p * 512 + tid) * 16;
    int r = o >> 7;
    int cb = (o & 127) ^ ((r & 7) << 4);
    async_copy16(Bb[0] + o, wg + (((size_t)r * D_) << 1) + cb);
  }
  __syncthreads();

  for (int t = 0; t < 32; t++) {
    int buf = t & 1;
    if (t < 31) {
      int k0 = (t + 1) * 64;
#pragma unroll
      for (int p = 0; p < 2; p++) {
        int o = (p * 512 + tid) * 16;
        int r = o >> 8;
        int cb = (o & 255) ^ ((r & 7) << 4);
        async_copy16(Ab[buf ^ 1] + o, xg + (((size_t)(row0 + r) * D_ + k0) << 2) + cb);
      }
#pragma unroll
      for (int p = 0; p < 6; p++) {
        int o = (p * 512 + tid) * 16;
        int r = o >> 7;
        int cb = (o & 127) ^ ((r & 7) << 4);
        async_copy16(Bb[buf ^ 1] + o, wg + (((size_t)r * D_ + k0) << 1) + cb);
      }
    }
    const char* A = Ab[buf];
    const char* Bp = Bb[buf];
#pragma unroll
    for (int ks = 0; ks < 2; ks++) {
      bf16x8 af[2], bfr[6];
#pragma unroll
      for (int mi = 0; mi < 2; mi++) {
        int r = wrow + mi * 16 + l15;
        int sw = (r & 7) << 4;
        int cb = ks * 128 + lhi * 32;
        float4 lo = *(const float4*)(A + r * 256 + (cb ^ sw));
        float4 hi = *(const float4*)(A + r * 256 + ((cb + 16) ^ sw));
        union { bf16x8 v; unsigned u[4]; } tt;
        tt.u[0] = cvt_pk_bf16(lo.x, lo.y);
        tt.u[1] = cvt_pk_bf16(lo.z, lo.w);
        tt.u[2] = cvt_pk_bf16(hi.x, hi.y);
        tt.u[3] = cvt_pk_bf16(hi.z, hi.w);
        af[mi] = tt.v;
      }
#pragma unroll
      for (int ni = 0; ni < 6; ni++) {
        int r = g * 96 + ni * 16 + l15;
        int sw = (r & 7) << 4;
        int cb = ks * 64 + lhi * 16;
        bfr[ni] = *(const bf16x8*)(Bp + r * 128 + (cb ^ sw));
      }
#pragma unroll
      for (int mi = 0; mi < 2; mi++)
#pragma unroll
        for (int ni = 0; ni < 6; ni++)
          acc[mi][ni] = __builtin_amdgcn_mfma_f32_16x16x32_bf16(af[mi], bfr[ni], acc[mi][ni], 0, 0, 0);
    }
    __syncthreads();
  }

  // epilogue: mats 0,1 (q,k): direct bf16 stores
#pragma unroll
  for (int ni = 0; ni < 4; ni++) {
    unsigned short* dst = (ni < 2) ? qo : ko;
    int nn = 32 * g + (ni & 1) * 16 + l15;
#pragma unroll
    for (int mi = 0; mi < 2; mi++)
#pragma unroll
      for (int r = 0; r < 4; r++) {
        int m = row0 + wrow + mi * 16 + lhi * 4 + r;
        dst[(size_t)m * H_ + nn] = f2bf(acc[mi][ni][r]);
      }
  }
  // mat 2 (V): transpose 32x32 per-wave tile via private LDS slice
  unsigned short* Tls = (unsigned short*)(Bb[0]) + w * 1280;  // [32][40]
#pragma unroll
  for (int ni = 4; ni < 6; ni++)
#pragma unroll
    for (int mi = 0; mi < 2; mi++)
#pragma unroll
      for (int r = 0; r < 4; r++)
        Tls[((ni - 4) * 16 + l15) * 40 + mi * 16 + lhi * 4 + r] = f2bf(acc[mi][ni][r]);
  // per-wave private region + in-order DS => no barrier needed
  {
    int b = row0 >> 12;
    int Lbase = (row0 & 4095) + wrow;
    int n_loc = lane >> 1;
    int half = (lane & 1) * 16;
    int h = 32 * g + n_loc;
#pragma unroll
    for (int j = 0; j < 2; j++) {
      bf16x8 v = *(const bf16x8*)&Tls[n_loc * 40 + half + j * 8];
      *(bf16x8*)&vt[(((size_t)(b * H_ + h)) << 12) + Lbase + half + j * 8] = v;
    }
  }
}

// ---------------------------------------------------------------------------
// Flash attention partials, swapped-QK^T (no LDS in loop, no shuffle softmax).
// Grid 2048: (b 4) x (chunk 4 x 1024 keys) x (q-tile 128 x 32 rows, heavy
// first). 4 waves/block, each wave owns 256 keys; block-combine via LDS.
// S^T = mfma32x32(K, Q): lane holds P[q=lane&31][16 of 32 keys, half=lane>>5].
// O^T = mfma32x32(V^T, P^T) accumulated per 32-h block.
// ---------------------------------------------------------------------------
__global__ __launch_bounds__(256) void attn(
    const unsigned short* __restrict__ q, const unsigned short* __restrict__ k,
    const unsigned short* __restrict__ vt, float* __restrict__ po,
    float* __restrict__ pm, float* __restrict__ pl) {
  int bid = blockIdx.x;
  int t = 127 - (bid & 127);
  int c = (bid >> 7) & 3;
  int b = bid >> 9;
  int cb = c << 10;
  int kcap = (t + 1) << 5;
  if (cb >= kcap) return;

  __shared__ float Ob[128][33];
  __shared__ float mls[4][32], lls[4][32];

  int tid = threadIdx.x;
  int w = tid >> 6, lane = tid & 63;
  int q31 = lane & 31;
  int hi = lane >> 5;
  int qt0 = t << 5;

  const unsigned short* qb = q + ((size_t)b << 12) * H_;
  const unsigned short* kb = k + ((size_t)b << 12) * H_;
  const unsigned short* vb = vt + ((size_t)b * H_ << 12);

  // Q fragments (B-operand of S^T): 8 k-steps of 16
  bf16x8 qf[8];
#pragma unroll
  for (int kk = 0; kk < 8; kk++)
    qf[kk] = *(const bf16x8*)&qb[(size_t)(qt0 + q31) * H_ + kk * 16 + hi * 8];

  f32x16 o[4];
#pragma unroll
  for (int hb = 0; hb < 4; hb++)
#pragma unroll
    for (int r = 0; r < 16; r++) o[hb][r] = 0.f;
  float mrun = -1e30f, lrun = 0.f;

  int kstart = cb + w * 256;
  int kend = min(cb + 1024, kcap);
  kend = min(kend, kstart + 256);
  int ntw = (kend > kstart) ? ((kend - kstart) >> 5) : 0;

  for (int ti = 0; ti < ntw; ti++) {
    int k0 = kstart + ti * 32;
    // --- S^T = K x Q^T ---
    f32x16 s;
#pragma unroll
    for (int r = 0; r < 16; r++) s[r] = 0.f;
    bf16x8 kf[8];
#pragma unroll
    for (int kk = 0; kk < 8; kk++)
      kf[kk] = *(const bf16x8*)&kb[(size_t)(k0 + q31) * H_ + kk * 16 + hi * 8];
#pragma unroll
    for (int kk = 0; kk < 8; kk++)
      s = __builtin_amdgcn_mfma_f32_32x32x16_bf16(kf[kk], qf[kk], s, 0, 0, 0);
    // --- V loads (independent of S; issue before softmax) ---
    bf16x8 vf[4][2];
#pragma unroll
    for (int hb = 0; hb < 4; hb++)
#pragma unroll
      for (int ks = 0; ks < 2; ks++)
        vf[hb][ks] = *(const bf16x8*)&vb[(size_t)(hb * 32 + q31) * L_ + k0 + ks * 16 + hi * 8];
    // --- causal mask (diagonal tile only) ---
    if (k0 == qt0) {
#pragma unroll
      for (int r = 0; r < 16; r++) {
        int kloc = (r & 3) + 8 * (r >> 2) + 4 * hi;
        if (kloc > q31) s[r] = -1e30f;
      }
    }
    // --- online softmax, in-register ---
    float m0 = fmaxf(s[0], s[1]), m1 = fmaxf(s[2], s[3]);
    float m2 = fmaxf(s[4], s[5]), m3 = fmaxf(s[6], s[7]);
    float m4 = fmaxf(s[8], s[9]), m5 = fmaxf(s[10], s[11]);
    float m6 = fmaxf(s[12], s[13]), m7 = fmaxf(s[14], s[15]);
    m0 = fmaxf(m0, m1); m2 = fmaxf(m2, m3); m4 = fmaxf(m4, m5); m6 = fmaxf(m6, m7);
    float mt = fmaxf(fmaxf(m0, m2), fmaxf(m4, m6));
    mt = fmaxf(mt, __shfl_xor(mt, 32, 64));
    if (!__all(mt <= mrun + 8.f)) {  // defer-max (T13)
      float mn = fmaxf(mrun, mt);
      float al = __expf(mrun - mn);
      mrun = mn;
      lrun *= al;
#pragma unroll
      for (int hb = 0; hb < 4; hb++)
#pragma unroll
        for (int r = 0; r < 16; r++) o[hb][r] *= al;
    }
    float p[16], ls = 0.f;
#pragma unroll
    for (int r = 0; r < 16; r++) {
      p[r] = __expf(s[r] - mrun);
      ls += p[r];
    }
    ls += __shfl_xor(ls, 32, 64);
    lrun += ls;
    // --- P^T -> B-fragments: cvt_pk + cross-half exchange ---
    unsigned c0 = cvt_pk_bf16(p[0], p[1]),   c1 = cvt_pk_bf16(p[2], p[3]);
    unsigned c2 = cvt_pk_bf16(p[4], p[5]),   c3 = cvt_pk_bf16(p[6], p[7]);
    unsigned c4 = cvt_pk_bf16(p[8], p[9]),   c5 = cvt_pk_bf16(p[10], p[11]);
    unsigned c6 = cvt_pk_bf16(p[12], p[13]), c7 = cvt_pk_bf16(p[14], p[15]);
    unsigned e0 = (unsigned)__shfl_xor((int)(hi ? c0 : c2), 32, 64);
    unsigned e1 = (unsigned)__shfl_xor((int)(hi ? c1 : c3), 32, 64);
    unsigned e2 = (unsigned)__shfl_xor((int)(hi ? c4 : c6), 32, 64);
    unsigned e3 = (unsigned)__shfl_xor((int)(hi ? c5 : c7), 32, 64);
    union { unsigned u[4]; bf16x8 v; } pb0, pb1;
    pb0.u[0] = hi ? e0 : c0; pb0.u[1] = hi ? e1 : c1;
    pb0.u[2] = hi ? c2 : e0; pb0.u[3] = hi ? c3 : e1;
    pb1.u[0] = hi ? e2 : c4; pb1.u[1] = hi ? e3 : c5;
    pb1.u[2] = hi ? c6 : e2; pb1.u[3] = hi ? c7 : e3;
    // --- O^T += V^T x P^T ---
#pragma unroll
    for (int hb = 0; hb < 4; hb++) {
      o[hb] = __builtin_amdgcn_mfma_f32_32x32x16_bf16(vf[hb][0], pb0.v, o[hb], 0, 0, 0);
      o[hb] = __builtin_amdgcn_mfma_f32_32x32x16_bf16(vf[hb][1], pb1.v, o[hb], 0, 0, 0);
    }
  }

  // --- block combine across 4 waves via LDS ---
  for (int idx = tid; idx < 128 * 33; idx += 256) ((float*)Ob)[idx] = 0.f;
  if (lane < 32) { mls[w][lane] = mrun; lls[w][lane] = lrun; }
  __syncthreads();
  float M = fmaxf(fmaxf(mls[0][q31], mls[1][q31]), fmaxf(mls[2][q31], mls[3][q31]));
  float al = __expf(mrun - M);
#pragma unroll
  for (int hb = 0; hb < 4; hb++)
#pragma unroll
    for (int r = 0; r < 16; r++) {
      int h = 32 * hb + (r & 3) + 8 * (r >> 2) + 4 * hi;
      atomicAdd(&Ob[h][q31], o[hb][r] * al);
    }
  __syncthreads();

  int slot = ((b << 7) + t) * 4 + c;
  float* pob = po + ((size_t)slot << 12);
  int qq = tid >> 3;
  int hc = (tid & 7) << 4;
#pragma unroll
  for (int j = 0; j < 16; j += 4) {
    float4 v;
    v.x = Ob[hc + j + 0][qq];
    v.y = Ob[hc + j + 1][qq];
    v.z = Ob[hc + j + 2][qq];
    v.w = Ob[hc + j + 3][qq];
    *(float4*)&pob[qq * 128 + hc + j] = v;
  }
  if (tid < 32) {
    float Mq = fmaxf(fmaxf(mls[0][tid], mls[1][tid]), fmaxf(mls[2][tid], mls[3][tid]));
    float Lq = 0.f;
#pragma unroll
    for (int ww = 0; ww < 4; ww++)
      Lq += lls[ww][tid] * __expf(mls[ww][tid] - Mq);
    pm[slot * 32 + tid] = Mq;
    pl[slot * 32 + tid] = Lq;
  }
}

// ---------------------------------------------------------------------------
// Combine partials: per (b, q-tile), merge <=4 chunks with rescale, normalize.
// ---------------------------------------------------------------------------
__global__ __launch_bounds__(256) void combine(
    const float* __restrict__ po, const float* __restrict__ pm,
    const float* __restrict__ pl, float* __restrict__ out) {
  int bid = blockIdx.x;  // b*128 + t
  int b = bid >> 7, t = bid & 127;
  int nc = (((t + 1) << 5) + 1023) >> 10;
  int tid = threadIdx.x;
  int row = tid >> 3;
  int hb = (tid & 7) << 4;
  int base = bid * 4;

  float M = -1e30f;
  for (int ci = 0; ci < nc; ci++) M = fmaxf(M, pm[(base + ci) * 32 + row]);
  float L = 0.f;
  float a[16];
#pragma unroll
  for (int j = 0; j < 16; j++) a[j] = 0.f;
  for (int ci = 0; ci < nc; ci++) {
    int sl = base + ci;
    float wgt = __expf(pm[sl * 32 + row] - M);
    L += pl[sl * 32 + row] * wgt;
    const float* p = po + ((size_t)sl << 12) + row * 128 + hb;
#pragma unroll
    for (int j = 0; j < 4; j++) {
      float4 v = *(const float4*)(p + j * 4);
      a[j * 4 + 0] += v.x * wgt;
      a[j * 4 + 1] += v.y * wgt;
      a[j * 4 + 2] += v.z * wgt;
      a[j * 4 + 3] += v.w * wgt;
    }
  }
  float inv = 1.f / L;
  float* ob = out + ((size_t)((b << 12) + (t << 5) + row)) * 128 + hb;
#pragma unroll
  for (int j = 0; j < 16; j++) ob[j] = a[j] * inv;
}

extern "C" void kernel_launch(void* const* d_in, const int* in_sizes, int n_in,
                              void* d_out, int out_size, void* d_ws, size_t ws_size,
                              hipStream_t stream) {
  const float* x  = (const float*)d_in[0];
  const float* Wq = (const float*)d_in[1];
  const float* Wk = (const float*)d_in[2];
  const float* Wv = (const float*)d_in[3];

  unsigned short* ws = (unsigned short*)d_ws;
  unsigned short* Wt = ws;                         // [384][2048] bf16 = 1.5 MB
  unsigned short* qo = ws + 786432;                // 4 MB
  unsigned short* ko = qo + (size_t)M_ * H_;       // 4 MB
  unsigned short* vt = ko + (size_t)M_ * H_;       // 4 MB
  float* po = (float*)(vt + (size_t)M_ * H_);      // 33.5 MB
  float* pm = po + (size_t)2048 * 4096;
  float* pl = pm + 2048 * 32;
  float* out = (float*)d_out;

  hipLaunchKernelGGL(wconv, dim3(3072), dim3(256), 0, stream, Wq, Wk, Wv, Wt);
  hipLaunchKernelGGL(qkv_gemm, dim3(256), dim3(512), 0, stream, x, Wt, qo, ko, vt);
  hipLaunchKernelGGL(attn, dim3(2048), dim3(256), 0, stream, qo, ko, vt, po, pm, pl);
  hipLaunchKernelGGL(combine, dim3(512), dim3(256), 0, stream, po, pm, pl, out);
}

// Round 4
// 286.881 us; speedup vs baseline: 1.7418x; 1.5052x over previous
//
#include <hip/hip_runtime.h>
#include <hip/hip_bf16.h>

#define B_ 4
#define L_ 4096
#define D_ 2048
#define H_ 128
#define M_ (B_ * L_)  // 16384

typedef __attribute__((ext_vector_type(8))) short bf16x8;
typedef __attribute__((ext_vector_type(4))) float f32x4;
typedef __attribute__((ext_vector_type(16))) float f32x16;

__device__ __forceinline__ unsigned short f2bf(float f) {
  union { float f; unsigned u; } v; v.f = f;
  unsigned r = v.u + 0x7FFFu + ((v.u >> 16) & 1u);
  return (unsigned short)(r >> 16);
}

__device__ __forceinline__ unsigned cvt_pk_bf16(float lo, float hi) {
  unsigned r;
  asm("v_cvt_pk_bf16_f32 %0, %1, %2" : "=v"(r) : "v"(lo), "v"(hi));
  return r;
}

__device__ __forceinline__ void async_copy16(void* lds, const void* gptr) {
  __builtin_amdgcn_global_load_lds(
      (const __attribute__((address_space(1))) unsigned int*)gptr,
      (__attribute__((address_space(3))) unsigned int*)lds, 16, 0, 0);
}

// ---------------------------------------------------------------------------
// Weight convert: Wt row R = 96*(n>>5) + 32*mat + (n&31), cols = d (bf16).
// 1/sqrt(128) folded into Wq.
// ---------------------------------------------------------------------------
__global__ void wconv(const float* __restrict__ Wq, const float* __restrict__ Wk,
                      const float* __restrict__ Wv, unsigned short* __restrict__ Wt) {
  int i = blockIdx.x * 256 + threadIdx.x;  // 3*128*2048
  int m = i >> 18;
  int rem = i & 262143;
  int n = rem >> 11;
  int d = rem & 2047;
  const float* W = (m == 0) ? Wq : (m == 1 ? Wk : Wv);
  float val = W[(size_t)d * H_ + n];
  if (m == 0) val *= 0.08838834764831845f;
  int R = 96 * (n >> 5) + 32 * m + (n & 31);
  Wt[(size_t)R * D_ + d] = f2bf(val);
}

// ---------------------------------------------------------------------------
// Fused QKV GEMM: x[16384,2048]fp32 @ Wt^T -> q,k [B*L][H] bf16, vt [B][H][L].
// BM=64, BN=384 (3 mats), BK=64, 512 thr (8 waves), double-buffered LDS,
// global_load_lds w16, XOR-swizzled (rule #21). launch_bounds(512,1): no
// VGPR squeeze (LDS already caps at 1 block/CU).
// ---------------------------------------------------------------------------
__global__ __launch_bounds__(512, 1) void qkv_gemm(
    const float* __restrict__ x, const unsigned short* __restrict__ Wt,
    unsigned short* __restrict__ qo, unsigned short* __restrict__ ko,
    unsigned short* __restrict__ vt) {
  __shared__ __align__(16) char Ab[2][16384];  // fp32 A [64][64] swizzled
  __shared__ __align__(16) char Bb[2][49152];  // bf16 B [384][64] swizzled

  int tid = threadIdx.x;
  int row0 = blockIdx.x * 64;
  int lane = tid & 63, w = tid >> 6;
  int wrow = (w >> 2) * 32;
  int g = w & 3;
  int l15 = lane & 15, lhi = lane >> 4;

  f32x4 zero = {0.f, 0.f, 0.f, 0.f};
  f32x4 acc[2][6];
#pragma unroll
  for (int i = 0; i < 2; i++)
#pragma unroll
    for (int j = 0; j < 6; j++) acc[i][j] = zero;

  const char* xg = (const char*)x;
  const char* wg = (const char*)Wt;

#pragma unroll
  for (int p = 0; p < 2; p++) {
    int o = (p * 512 + tid) * 16;
    int r = o >> 8;
    int cb = (o & 255) ^ ((r & 7) << 4);
    async_copy16(Ab[0] + o, xg + (((size_t)(row0 + r) * D_) << 2) + cb);
  }
#pragma unroll
  for (int p = 0; p < 6; p++) {
    int o = (p * 512 + tid) * 16;
    int r = o >> 7;
    int cb = (o & 127) ^ ((r & 7) << 4);
    async_copy16(Bb[0] + o, wg + (((size_t)r * D_) << 1) + cb);
  }
  __syncthreads();

  for (int t = 0; t < 32; t++) {
    int buf = t & 1;
    if (t < 31) {
      int k0 = (t + 1) * 64;
#pragma unroll
      for (int p = 0; p < 2; p++) {
        int o = (p * 512 + tid) * 16;
        int r = o >> 8;
        int cb = (o & 255) ^ ((r & 7) << 4);
        async_copy16(Ab[buf ^ 1] + o, xg + (((size_t)(row0 + r) * D_ + k0) << 2) + cb);
      }
#pragma unroll
      for (int p = 0; p < 6; p++) {
        int o = (p * 512 + tid) * 16;
        int r = o >> 7;
        int cb = (o & 127) ^ ((r & 7) << 4);
        async_copy16(Bb[buf ^ 1] + o, wg + (((size_t)r * D_ + k0) << 1) + cb);
      }
    }
    const char* A = Ab[buf];
    const char* Bp = Bb[buf];
#pragma unroll
    for (int ks = 0; ks < 2; ks++) {
      bf16x8 af[2], bfr[6];
#pragma unroll
      for (int mi = 0; mi < 2; mi++) {
        int r = wrow + mi * 16 + l15;
        int sw = (r & 7) << 4;
        int cb = ks * 128 + lhi * 32;
        float4 lo = *(const float4*)(A + r * 256 + (cb ^ sw));
        float4 hi = *(const float4*)(A + r * 256 + ((cb + 16) ^ sw));
        union { bf16x8 v; unsigned u[4]; } tt;
        tt.u[0] = cvt_pk_bf16(lo.x, lo.y);
        tt.u[1] = cvt_pk_bf16(lo.z, lo.w);
        tt.u[2] = cvt_pk_bf16(hi.x, hi.y);
        tt.u[3] = cvt_pk_bf16(hi.z, hi.w);
        af[mi] = tt.v;
      }
#pragma unroll
      for (int ni = 0; ni < 6; ni++) {
        int r = g * 96 + ni * 16 + l15;
        int sw = (r & 7) << 4;
        int cb = ks * 64 + lhi * 16;
        bfr[ni] = *(const bf16x8*)(Bp + r * 128 + (cb ^ sw));
      }
#pragma unroll
      for (int mi = 0; mi < 2; mi++)
#pragma unroll
        for (int ni = 0; ni < 6; ni++)
          acc[mi][ni] = __builtin_amdgcn_mfma_f32_16x16x32_bf16(af[mi], bfr[ni], acc[mi][ni], 0, 0, 0);
    }
    __syncthreads();
  }

#pragma unroll
  for (int ni = 0; ni < 4; ni++) {
    unsigned short* dst = (ni < 2) ? qo : ko;
    int nn = 32 * g + (ni & 1) * 16 + l15;
#pragma unroll
    for (int mi = 0; mi < 2; mi++)
#pragma unroll
      for (int r = 0; r < 4; r++) {
        int m = row0 + wrow + mi * 16 + lhi * 4 + r;
        dst[(size_t)m * H_ + nn] = f2bf(acc[mi][ni][r]);
      }
  }
  unsigned short* Tls = (unsigned short*)(Bb[0]) + w * 1280;  // [32][40]
#pragma unroll
  for (int ni = 4; ni < 6; ni++)
#pragma unroll
    for (int mi = 0; mi < 2; mi++)
#pragma unroll
      for (int r = 0; r < 4; r++)
        Tls[((ni - 4) * 16 + l15) * 40 + mi * 16 + lhi * 4 + r] = f2bf(acc[mi][ni][r]);
  {
    int b = row0 >> 12;
    int Lbase = (row0 & 4095) + wrow;
    int n_loc = lane >> 1;
    int half = (lane & 1) * 16;
    int h = 32 * g + n_loc;
#pragma unroll
    for (int j = 0; j < 2; j++) {
      bf16x8 v = *(const bf16x8*)&Tls[n_loc * 40 + half + j * 8];
      *(bf16x8*)&vt[(((size_t)(b * H_ + h)) << 12) + Lbase + half + j * 8] = v;
    }
  }
}

// ---------------------------------------------------------------------------
// Flash attention partials. Block = 128 q-rows (4 waves x 32) x 1024-key
// chunk; K/V tiles (64 keys) double-buffered in LDS, shared by all 4 waves.
// Swapped QK^T (32x32 MFMA), in-register softmax, no spills
// (launch_bounds(256,2) => 256 VGPR cap, live ~140).
// Grid 320: (80 heavy-first (j,c) pairs) x 4 batches.
// ---------------------------------------------------------------------------
__global__ __launch_bounds__(256, 2) void attn(
    const unsigned short* __restrict__ q, const unsigned short* __restrict__ k,
    const unsigned short* __restrict__ vt, float* __restrict__ po,
    float* __restrict__ pm, float* __restrict__ pl) {
  __shared__ __align__(16) char Kb[2][16384];  // K tile [64 keys][128 d] bf16, swizzled
  __shared__ __align__(16) char Vb[2][16384];  // V^T tile [128 h][64 keys] bf16, swizzled

  int bid = blockIdx.x;
  int b = bid & 3;
  int p2 = bid >> 2;  // 0..79, heavy-first
  int j, c;
  if (p2 < 32)      { j = 31 - (p2 >> 2);            c = p2 & 3; }
  else if (p2 < 56) { int i = p2 - 32; int d3 = i / 3; j = 23 - d3; c = i - 3 * d3; }
  else if (p2 < 72) { int i = p2 - 56; j = 15 - (i >> 1); c = i & 1; }
  else              { j = 7 - (p2 - 72);             c = 0; }

  int kbase = c << 10;
  int kmax = min((c + 1) << 10, (j + 1) << 7);
  int NT = (kmax - kbase) >> 6;

  int tid = threadIdx.x;
  int w = tid >> 6, lane = tid & 63;
  int q31 = lane & 31, hi = lane >> 5;
  int qw0 = (j << 7) + (w << 5);  // this wave's 32 q-rows
  int kcap = qw0 + 32;

  const unsigned short* qb = q + ((size_t)b << 12) * H_;
  const char* kbyte = (const char*)(k + ((size_t)b << 12) * H_);
  const char* vbyte = (const char*)(vt + ((size_t)b * H_ << 12));

  // Q fragments in registers (B-operand of S^T), 32 VGPR, loaded once
  bf16x8 qf[8];
#pragma unroll
  for (int kk = 0; kk < 8; kk++)
    qf[kk] = *(const bf16x8*)&qb[(size_t)(qw0 + q31) * H_ + kk * 16 + hi * 8];

  f32x16 o[4];
#pragma unroll
  for (int hb = 0; hb < 4; hb++)
#pragma unroll
    for (int r = 0; r < 16; r++) o[hb][r] = 0.f;
  float mrun = -1e30f, lrun = 0.f;

  int ksw = (q31 & 7) << 4;

  // ---- staging macro: K 16KB + V 16KB per 64-key tile, all 256 threads ----
#define STAGE(bi, k0)                                                          \
  {                                                                            \
    _Pragma("unroll") for (int p = 0; p < 4; p++) {                            \
      int oo = (p * 256 + tid) * 16;                                           \
      int rr = oo >> 8;                                                        \
      int cc = (oo & 255) ^ ((rr & 7) << 4);                                   \
      async_copy16(Kb[bi] + oo, kbyte + (size_t)((k0) + rr) * 256 + cc);       \
    }                                                                          \
    _Pragma("unroll") for (int p = 0; p < 4; p++) {                            \
      int oo = (p * 256 + tid) * 16;                                           \
      int hh = oo >> 7;                                                        \
      int cc = (oo & 127) ^ ((hh & 7) << 4);                                   \
      async_copy16(Vb[bi] + oo, vbyte + (size_t)hh * 8192 + (size_t)(k0) * 2 + cc); \
    }                                                                          \
  }

  STAGE(0, kbase);

  for (int t = 0; t < NT; t++) {
    __syncthreads();  // drains vmcnt(0): buf[t&1] staged; prior ds_reads done
    int k0 = kbase + (t << 6);
    if (t + 1 < NT) STAGE((t + 1) & 1, k0 + 64);
    const char* Kc = Kb[t & 1];
    const char* Vc = Vb[t & 1];

#pragma unroll
    for (int sub = 0; sub < 2; sub++) {
      int k0s = k0 + (sub << 5);
      if (k0s < kcap) {
        int kloc2 = sub << 5;
        const char* Krow = Kc + (kloc2 + q31) * 256;
        f32x16 s;
#pragma unroll
        for (int r = 0; r < 16; r++) s[r] = 0.f;
#pragma unroll
        for (int kk = 0; kk < 8; kk++) {
          bf16x8 kf = *(const bf16x8*)(Krow + ((kk * 32 + hi * 16) ^ ksw));
          s = __builtin_amdgcn_mfma_f32_32x32x16_bf16(kf, qf[kk], s, 0, 0, 0);
        }
        if (k0s == qw0) {  // diagonal: mask key > q
#pragma unroll
          for (int r = 0; r < 16; r++) {
            int kloc = (r & 3) + 8 * (r >> 2) + 4 * hi;
            if (kloc > q31) s[r] = -1e30f;
          }
        }
        // online softmax (in-register, one cross-half shfl)
        float m0 = fmaxf(fmaxf(s[0], s[1]), fmaxf(s[2], s[3]));
        float m1 = fmaxf(fmaxf(s[4], s[5]), fmaxf(s[6], s[7]));
        float m2 = fmaxf(fmaxf(s[8], s[9]), fmaxf(s[10], s[11]));
        float m3 = fmaxf(fmaxf(s[12], s[13]), fmaxf(s[14], s[15]));
        float mt = fmaxf(fmaxf(m0, m1), fmaxf(m2, m3));
        mt = fmaxf(mt, __shfl_xor(mt, 32, 64));
        if (!__all(mt <= mrun + 8.f)) {  // defer-max (T13)
          float mn = fmaxf(mrun, mt);
          float al = __expf(mrun - mn);
          mrun = mn;
          lrun *= al;
#pragma unroll
          for (int hb = 0; hb < 4; hb++)
#pragma unroll
            for (int r = 0; r < 16; r++) o[hb][r] *= al;
        }
        float p[16], ls = 0.f;
#pragma unroll
        for (int r = 0; r < 16; r++) {
          p[r] = __expf(s[r] - mrun);
          ls += p[r];
        }
        ls += __shfl_xor(ls, 32, 64);
        lrun += ls;
        // P^T -> B-fragments
        unsigned c0 = cvt_pk_bf16(p[0], p[1]),   c1 = cvt_pk_bf16(p[2], p[3]);
        unsigned c2 = cvt_pk_bf16(p[4], p[5]),   c3 = cvt_pk_bf16(p[6], p[7]);
        unsigned c4 = cvt_pk_bf16(p[8], p[9]),   c5 = cvt_pk_bf16(p[10], p[11]);
        unsigned c6 = cvt_pk_bf16(p[12], p[13]), c7 = cvt_pk_bf16(p[14], p[15]);
        unsigned e0 = (unsigned)__shfl_xor((int)(hi ? c0 : c2), 32, 64);
        unsigned e1 = (unsigned)__shfl_xor((int)(hi ? c1 : c3), 32, 64);
        unsigned e2 = (unsigned)__shfl_xor((int)(hi ? c4 : c6), 32, 64);
        unsigned e3 = (unsigned)__shfl_xor((int)(hi ? c5 : c7), 32, 64);
        union { unsigned u[4]; bf16x8 v; } pb0, pb1;
        pb0.u[0] = hi ? e0 : c0; pb0.u[1] = hi ? e1 : c1;
        pb0.u[2] = hi ? c2 : e0; pb0.u[3] = hi ? c3 : e1;
        pb1.u[0] = hi ? e2 : c4; pb1.u[1] = hi ? e3 : c5;
        pb1.u[2] = hi ? c6 : e2; pb1.u[3] = hi ? c7 : e3;
        // O^T += V^T x P^T (V from LDS just-in-time)
#pragma unroll
        for (int hb = 0; hb < 4; hb++) {
          const char* Vrow = Vc + (hb * 32 + q31) * 128;
          bf16x8 v0 = *(const bf16x8*)(Vrow + ((kloc2 * 2 + hi * 16) ^ ksw));
          bf16x8 v1 = *(const bf16x8*)(Vrow + ((kloc2 * 2 + 32 + hi * 16) ^ ksw));
          o[hb] = __builtin_amdgcn_mfma_f32_32x32x16_bf16(v0, pb0.v, o[hb], 0, 0, 0);
          o[hb] = __builtin_amdgcn_mfma_f32_32x32x16_bf16(v1, pb1.v, o[hb], 0, 0, 0);
        }
      }
    }
  }
#undef STAGE

  // write partials: slot = ((b*128 + qtile)*4 + c), layout [32 q][128 h] f32
  int qtile = (j << 2) + w;
  int slot = (((b << 7) + qtile) << 2) + c;
  float* pob = po + ((size_t)slot << 12);
#pragma unroll
  for (int hb = 0; hb < 4; hb++)
#pragma unroll
    for (int rq = 0; rq < 4; rq++) {
      float4 v;
      v.x = o[hb][rq * 4 + 0];
      v.y = o[hb][rq * 4 + 1];
      v.z = o[hb][rq * 4 + 2];
      v.w = o[hb][rq * 4 + 3];
      *(float4*)&pob[q31 * 128 + 32 * hb + 8 * rq + 4 * hi] = v;
    }
  if (lane < 32) {
    pm[slot * 32 + q31] = mrun;
    pl[slot * 32 + q31] = lrun;
  }
}

// ---------------------------------------------------------------------------
// Combine partials: per (b, q-tile), merge <=4 chunks with rescale, normalize.
// ---------------------------------------------------------------------------
__global__ __launch_bounds__(256) void combine(
    const float* __restrict__ po, const float* __restrict__ pm,
    const float* __restrict__ pl, float* __restrict__ out) {
  int bid = blockIdx.x;  // b*128 + t
  int b = bid >> 7, t = bid & 127;
  int nc = (((t + 1) << 5) + 1023) >> 10;
  int tid = threadIdx.x;
  int row = tid >> 3;
  int hb = (tid & 7) << 4;
  int base = bid * 4;

  float M = -1e30f;
  for (int ci = 0; ci < nc; ci++) M = fmaxf(M, pm[(base + ci) * 32 + row]);
  float L = 0.f;
  float a[16];
#pragma unroll
  for (int j = 0; j < 16; j++) a[j] = 0.f;
  for (int ci = 0; ci < nc; ci++) {
    int sl = base + ci;
    float wgt = __expf(pm[sl * 32 + row] - M);
    L += pl[sl * 32 + row] * wgt;
    const float* p = po + ((size_t)sl << 12) + row * 128 + hb;
#pragma unroll
    for (int j = 0; j < 4; j++) {
      float4 v = *(const float4*)(p + j * 4);
      a[j * 4 + 0] += v.x * wgt;
      a[j * 4 + 1] += v.y * wgt;
      a[j * 4 + 2] += v.z * wgt;
      a[j * 4 + 3] += v.w * wgt;
    }
  }
  float inv = 1.f / L;
  float* ob = out + ((size_t)((b << 12) + (t << 5) + row)) * 128 + hb;
#pragma unroll
  for (int j = 0; j < 16; j++) ob[j] = a[j] * inv;
}

extern "C" void kernel_launch(void* const* d_in, const int* in_sizes, int n_in,
                              void* d_out, int out_size, void* d_ws, size_t ws_size,
                              hipStream_t stream) {
  const float* x  = (const float*)d_in[0];
  const float* Wq = (const float*)d_in[1];
  const float* Wk = (const float*)d_in[2];
  const float* Wv = (const float*)d_in[3];

  unsigned short* ws = (unsigned short*)d_ws;
  unsigned short* Wt = ws;                         // [384][2048] bf16 = 1.5 MB
  unsigned short* qo = ws + 786432;                // 4 MB
  unsigned short* ko = qo + (size_t)M_ * H_;       // 4 MB
  unsigned short* vt = ko + (size_t)M_ * H_;       // 4 MB
  float* po = (float*)(vt + (size_t)M_ * H_);      // 33.5 MB
  float* pm = po + (size_t)2048 * 4096;
  float* pl = pm + 2048 * 32;
  float* out = (float*)d_out;

  hipLaunchKernelGGL(wconv, dim3(3072), dim3(256), 0, stream, Wq, Wk, Wv, Wt);
  hipLaunchKernelGGL(qkv_gemm, dim3(256), dim3(512), 0, stream, x, Wt, qo, ko, vt);
  hipLaunchKernelGGL(attn, dim3(320), dim3(256), 0, stream, qo, ko, vt, po, pm, pl);
  hipLaunchKernelGGL(combine, dim3(512), dim3(256), 0, stream, po, pm, pl, out);
}